// Round 18
// baseline (470.757 us; speedup 1.0000x reference)
//
#include <hip/hip_runtime.h>

#define NN 512
#define DD 64
#define BB 64
#define ND (NN * DD)          // 32768

static const long BND = (long)BB * ND;   // 2,097,152

typedef __bf16 bf16x8 __attribute__((ext_vector_type(8)));
typedef float  f32x4  __attribute__((ext_vector_type(4)));

__device__ __forceinline__ float bf2f(unsigned short u) {
    return __uint_as_float(((unsigned int)u) << 16);
}
// fp32 -> hi/lo bf16 split via native casts (HW v_cvt_pk_bf16_f32, RNE)
__device__ __forceinline__ void cvt4(const float4& x, ushort4& h, ushort4& l) {
    __bf16 h0 = (__bf16)x.x, h1 = (__bf16)x.y, h2 = (__bf16)x.z, h3 = (__bf16)x.w;
    __bf16 l0 = (__bf16)(x.x - (float)h0);
    __bf16 l1 = (__bf16)(x.y - (float)h1);
    __bf16 l2 = (__bf16)(x.z - (float)h2);
    __bf16 l3 = (__bf16)(x.w - (float)h3);
    h = make_ushort4(__builtin_bit_cast(unsigned short, h0),
                     __builtin_bit_cast(unsigned short, h1),
                     __builtin_bit_cast(unsigned short, h2),
                     __builtin_bit_cast(unsigned short, h3));
    l = make_ushort4(__builtin_bit_cast(unsigned short, l0),
                     __builtin_bit_cast(unsigned short, l1),
                     __builtin_bit_cast(unsigned short, l2),
                     __builtin_bit_cast(unsigned short, l3));
}
__device__ __forceinline__ bf16x8 ld_bf8(const unsigned short* p) {
    int4 v = *reinterpret_cast<const int4*>(p);
    return __builtin_bit_cast(bf16x8, v);
}
__device__ __forceinline__ f32x4 mfma16(bf16x8 a, bf16x8 b, f32x4 c) {
    return __builtin_amdgcn_mfma_f32_16x16x32_bf16(a, b, c, 0, 0, 0);
}
// LDS tile [r][64 shorts], XOR swizzle (0 bank conflicts, R2-proven)
__device__ __forceinline__ int swzW4(int r, int c) {   // c = ushort4 group 0..15
    return r * 64 + (((c >> 1) ^ (r & 7)) << 3) + ((c & 1) << 2);
}
__device__ __forceinline__ int swzR(int r, int oct) {  // oct 0..7
    return r * 64 + ((oct ^ (r & 7)) << 3);
}

// ---------------------------------------------------------------------------
// gemm_z3 (R17-exact): Z-GEMM, z-triple fused.
// ---------------------------------------------------------------------------
__global__ __launch_bounds__(512) void gemm_z3(
    const float* __restrict__ Afp, int lda, long aBatch,
    const unsigned short* __restrict__ Wh, const unsigned short* __restrict__ Wl,
    int kdim, float* __restrict__ out, long outZ)
{
    const int nwg = gridDim.x;
    const int lid = (blockIdx.x & 7) * (nwg >> 3) + (blockIdx.x >> 3);
    const int zp  = lid & 1;
    const int t2  = lid >> 1;
    const int i0  = (t2 & 7) << 6;
    const int b   = t2 >> 3;

    const float* __restrict__ Ab = Afp + (long)b * aBatch;
    const unsigned short* __restrict__ W0h = Wh + (long)(zp * 3 + 0) * 64 * kdim;
    const unsigned short* __restrict__ W0l = Wl + (long)(zp * 3 + 0) * 64 * kdim;
    const unsigned short* __restrict__ W1h = Wh + (long)(zp * 3 + 1) * 64 * kdim;
    const unsigned short* __restrict__ W1l = Wl + (long)(zp * 3 + 1) * 64 * kdim;
    const unsigned short* __restrict__ W2h = Wh + (long)(zp * 3 + 2) * 64 * kdim;
    const unsigned short* __restrict__ W2l = Wl + (long)(zp * 3 + 2) * 64 * kdim;

    __shared__ __align__(16) unsigned short sXh[4096];
    __shared__ __align__(16) unsigned short sXl[4096];
    __shared__ __align__(16) unsigned short sW0h[4096];
    __shared__ __align__(16) unsigned short sW0l[4096];
    __shared__ __align__(16) unsigned short sW1h[4096];
    __shared__ __align__(16) unsigned short sW1l[4096];
    __shared__ __align__(16) unsigned short sW2h[4096];
    __shared__ __align__(16) unsigned short sW2l[4096];

    const int t = threadIdx.x;
    const int w = t >> 6, lane = t & 63;
    const int wr = w >> 1, wc = w & 1;
    const int lr = lane & 15, lg = lane >> 4;

    f32x4 acc[3][2];
#pragma unroll
    for (int zz = 0; zz < 3; ++zz)
#pragma unroll
        for (int n = 0; n < 2; ++n) acc[zz][n] = f32x4{0.f, 0.f, 0.f, 0.f};

    const int steps = kdim >> 6;
    const int rW = t >> 3, jW = t & 7;
    const int widx = rW * 64 + ((jW ^ (rW & 7)) << 3);
    const long wsrc0 = (long)rW * kdim + jW * 8;

    float4 ra[2];
    int4 w0h, w0l, w1h, w1l, w2h, w2l;

#pragma unroll
    for (int l = 0; l < 2; ++l) {
        int q = t + l * 512, r = q >> 4, c = q & 15;
        ra[l] = *reinterpret_cast<const float4*>(Ab + (long)(i0 + r) * lda + c * 4);
    }
    w0h = *reinterpret_cast<const int4*>(W0h + wsrc0);
    w0l = *reinterpret_cast<const int4*>(W0l + wsrc0);
    w1h = *reinterpret_cast<const int4*>(W1h + wsrc0);
    w1l = *reinterpret_cast<const int4*>(W1l + wsrc0);
    w2h = *reinterpret_cast<const int4*>(W2h + wsrc0);
    w2l = *reinterpret_cast<const int4*>(W2l + wsrc0);

    for (int s = 0; s < steps; ++s) {
        if (s) __syncthreads();
#pragma unroll
        for (int l = 0; l < 2; ++l) {
            int q = t + l * 512, r = q >> 4, c = q & 15;
            int idx = swzW4(r, c);
            ushort4 h4, l4;
            cvt4(ra[l], h4, l4);
            *reinterpret_cast<ushort4*>(&sXh[idx]) = h4;
            *reinterpret_cast<ushort4*>(&sXl[idx]) = l4;
        }
        *reinterpret_cast<int4*>(&sW0h[widx]) = w0h;
        *reinterpret_cast<int4*>(&sW0l[widx]) = w0l;
        *reinterpret_cast<int4*>(&sW1h[widx]) = w1h;
        *reinterpret_cast<int4*>(&sW1l[widx]) = w1l;
        *reinterpret_cast<int4*>(&sW2h[widx]) = w2h;
        *reinterpret_cast<int4*>(&sW2l[widx]) = w2l;
        __syncthreads();
        if (s + 1 < steps) {
            const int k0n = (s + 1) << 6;
#pragma unroll
            for (int l = 0; l < 2; ++l) {
                int q = t + l * 512, r = q >> 4, c = q & 15;
                ra[l] = *reinterpret_cast<const float4*>(Ab + (long)(i0 + r) * lda + k0n + c * 4);
            }
            w0h = *reinterpret_cast<const int4*>(W0h + wsrc0 + k0n);
            w0l = *reinterpret_cast<const int4*>(W0l + wsrc0 + k0n);
            w1h = *reinterpret_cast<const int4*>(W1h + wsrc0 + k0n);
            w1l = *reinterpret_cast<const int4*>(W1l + wsrc0 + k0n);
            w2h = *reinterpret_cast<const int4*>(W2h + wsrc0 + k0n);
            w2l = *reinterpret_cast<const int4*>(W2l + wsrc0 + k0n);
        }
#pragma unroll
        for (int c2 = 0; c2 < 2; ++c2) {
            const int oct = c2 * 4 + lg;
            const int arow = wr * 16 + lr;
            bf16x8 a_h = ld_bf8(&sXh[swzR(arow, oct)]);
            bf16x8 a_l = ld_bf8(&sXl[swzR(arow, oct)]);
#pragma unroll
            for (int n = 0; n < 2; ++n) {
                const int col = wc * 32 + n * 16 + lr;
                const int ci = swzR(col, oct);
                bf16x8 b0h = ld_bf8(&sW0h[ci]);
                bf16x8 b0l = ld_bf8(&sW0l[ci]);
                acc[0][n] = mfma16(a_h, b0h, acc[0][n]);
                acc[0][n] = mfma16(a_h, b0l, acc[0][n]);
                acc[0][n] = mfma16(a_l, b0h, acc[0][n]);
                bf16x8 b1h = ld_bf8(&sW1h[ci]);
                bf16x8 b1l = ld_bf8(&sW1l[ci]);
                acc[1][n] = mfma16(a_h, b1h, acc[1][n]);
                acc[1][n] = mfma16(a_h, b1l, acc[1][n]);
                acc[1][n] = mfma16(a_l, b1h, acc[1][n]);
                bf16x8 b2h = ld_bf8(&sW2h[ci]);
                bf16x8 b2l = ld_bf8(&sW2l[ci]);
                acc[2][n] = mfma16(a_h, b2h, acc[2][n]);
                acc[2][n] = mfma16(a_h, b2l, acc[2][n]);
                acc[2][n] = mfma16(a_l, b2h, acc[2][n]);
            }
        }
    }

    const long cOff = (long)b * ND;
    const int nb = i0 + wr * 16 + lg * 4;
#pragma unroll
    for (int zz = 0; zz < 3; ++zz) {
        const long oOff = (long)(zp * 3 + zz) * outZ + cOff;
#pragma unroll
        for (int n = 0; n < 2; ++n) {
            const int f = wc * 32 + n * 16 + lr;
            float4 v;
            v.x = acc[zz][n][0]; v.y = acc[zz][n][1];
            v.z = acc[zz][n][2]; v.w = acc[zz][n][3];
            *reinterpret_cast<float4*>(out + oOff + (long)f * NN + nb) = v;
        }
    }
}

// ---------------------------------------------------------------------------
// cheb GEMM v18: HALF-TILE (32 rows x 64 cols), 1024 blocks -> 4 blk/CU =
// 100% wave occupancy (LDS 24 KB, wave-slot capped).  8 waves = 2 row-strips
// x 4 col-strips, each 16x16, acc = one f32x4, 6 MFMA/step.  Same proven
// staging/swizzle/epilogue formulas; XCD-chunked 1D grid (i0 fastest).
// ---------------------------------------------------------------------------
template <bool HAS_VM, bool HAS_Z, bool HAS_BIAS, bool OUT_ROW>
__global__ __launch_bounds__(512) void gemm_mfma(
    const float* __restrict__ A, int lda, long aBatch,
    const float* __restrict__ U, long uBatch,
    const float* __restrict__ Vm, const float* __restrict__ Zt,
    const float* __restrict__ bias, float alpha, float beta, int kdim,
    float* __restrict__ out)
{
    const int nwg = gridDim.x;
    const int lid = (blockIdx.x & 7) * (nwg >> 3) + (blockIdx.x >> 3);
    const int i0  = (lid & 15) << 5;          // 16 x 32-row tiles, fastest
    const int b   = lid >> 4;

    const float* __restrict__ Ab = A + (long)b * aBatch;
    const float* __restrict__ Ub = U + (long)b * uBatch;

    __shared__ __align__(16) unsigned short sAh[2048];   // [32][64]
    __shared__ __align__(16) unsigned short sAl[2048];
    __shared__ __align__(16) unsigned short sBh[4096];   // [64][64]
    __shared__ __align__(16) unsigned short sBl[4096];

    const int t = threadIdx.x;
    const int w = t >> 6, lane = t & 63;
    const int wr = w >> 2, wc = w & 3;        // 2 row-strips x 4 col-strips
    const int lr = lane & 15, lg = lane >> 4;

    f32x4 acc = f32x4{0.f, 0.f, 0.f, 0.f};

    const int steps = kdim >> 6;
    float4 ra;        // 512 thr x 1 float4 = 32x64 floats
    float4 rb[2];     // 512 thr x 2 float4 = 64x64 floats

    {
        int r = t >> 4, c = t & 15;
        ra = *reinterpret_cast<const float4*>(Ab + (long)(i0 + r) * lda + c * 4);
    }
#pragma unroll
    for (int l = 0; l < 2; ++l) {
        int q = t + l * 512, r = q >> 4, c = q & 15;
        rb[l] = *reinterpret_cast<const float4*>(Ub + (long)r * kdim + c * 4);
    }

    for (int s = 0; s < steps; ++s) {
        if (s) __syncthreads();
        {
            int r = t >> 4, c = t & 15;
            int idx = swzW4(r, c);
            ushort4 h4, l4;
            cvt4(ra, h4, l4);
            *reinterpret_cast<ushort4*>(&sAh[idx]) = h4;
            *reinterpret_cast<ushort4*>(&sAl[idx]) = l4;
        }
#pragma unroll
        for (int l = 0; l < 2; ++l) {
            int q = t + l * 512, r = q >> 4, c = q & 15;
            int idx = swzW4(r, c);
            ushort4 h4, l4;
            cvt4(rb[l], h4, l4);
            *reinterpret_cast<ushort4*>(&sBh[idx]) = h4;
            *reinterpret_cast<ushort4*>(&sBl[idx]) = l4;
        }
        __syncthreads();
        if (s + 1 < steps) {
            const int k0n = (s + 1) << 6;
            {
                int r = t >> 4, c = t & 15;
                ra = *reinterpret_cast<const float4*>(Ab + (long)(i0 + r) * lda + k0n + c * 4);
            }
#pragma unroll
            for (int l = 0; l < 2; ++l) {
                int q = t + l * 512, r = q >> 4, c = q & 15;
                rb[l] = *reinterpret_cast<const float4*>(Ub + (long)r * kdim + k0n + c * 4);
            }
        }
#pragma unroll
        for (int c2 = 0; c2 < 2; ++c2) {
            const int oct = c2 * 4 + lg;
            const int arow = wr * 16 + lr;
            bf16x8 a_h = ld_bf8(&sAh[swzR(arow, oct)]);
            bf16x8 a_l = ld_bf8(&sAl[swzR(arow, oct)]);
            const int col = wc * 16 + lr;
            bf16x8 b_h = ld_bf8(&sBh[swzR(col, oct)]);
            bf16x8 b_l = ld_bf8(&sBl[swzR(col, oct)]);
            acc = mfma16(a_h, b_h, acc);
            acc = mfma16(a_h, b_l, acc);
            acc = mfma16(a_l, b_h, acc);
        }
    }

    // epilogue: col = lane&15, row = (lane>>4)*4 + reg (proven mapping)
    const long cOff = (long)b * ND;
    const int nb = i0 + wr * 16 + lg * 4;
    const int f = wc * 16 + lr;
    float4 v;
    v.x = alpha * acc[0]; v.y = alpha * acc[1];
    v.z = alpha * acc[2]; v.w = alpha * acc[3];
    if (HAS_VM) {
        float4 mv = *reinterpret_cast<const float4*>(Vm + cOff + (long)f * NN + nb);
        v.x += beta * mv.x; v.y += beta * mv.y; v.z += beta * mv.z; v.w += beta * mv.w;
    }
    if (HAS_Z) {
        float4 zz = *reinterpret_cast<const float4*>(Zt + cOff + (long)f * NN + nb);
        v.x += zz.x; v.y += zz.y; v.z += zz.z; v.w += zz.w;
    }
    if (HAS_BIAS) {
        float bf = bias[f];
        v.x += bf; v.y += bf; v.z += bf; v.w += bf;
    }
    if (OUT_ROW) {
        float* __restrict__ outb = out + cOff;
        outb[(long)(nb + 0) * DD + f] = v.x;
        outb[(long)(nb + 1) * DD + f] = v.y;
        outb[(long)(nb + 2) * DD + f] = v.z;
        outb[(long)(nb + 3) * DD + f] = v.w;
    } else {
        *reinterpret_cast<float4*>(out + cOff + (long)f * NN + nb) = v;
    }
}

// ---------------------------------------------------------------------------
// AE = relu(X0 X0^T), diag zeroed (R17-exact). X0 fp32 row-major [512][64].
// ---------------------------------------------------------------------------
__global__ __launch_bounds__(256) void outer_v18(
    const float* __restrict__ X0, float* __restrict__ AE)
{
    const int b = blockIdx.z;
    const int j0 = blockIdx.x * 64, i0 = blockIdx.y * 64;
    const float* __restrict__ Xb = X0 + (long)b * ND;

    __shared__ __align__(16) unsigned short sIh[4096];
    __shared__ __align__(16) unsigned short sIl[4096];
    __shared__ __align__(16) unsigned short sJh[4096];
    __shared__ __align__(16) unsigned short sJl[4096];

    const int t = threadIdx.x;
    const int w = t >> 6, lane = t & 63;
    const int wr = w >> 1, wc = w & 1;
    const int lr = lane & 15, lg = lane >> 4;

#pragma unroll
    for (int l = 0; l < 4; ++l) {
        int q = t + l * 256;
        int r = q >> 4, c = q & 15;
        int idx = swzW4(r, c);
        ushort4 h4, l4;
        float4 vi = *reinterpret_cast<const float4*>(Xb + (long)(i0 + r) * DD + c * 4);
        cvt4(vi, h4, l4);
        *reinterpret_cast<ushort4*>(&sIh[idx]) = h4;
        *reinterpret_cast<ushort4*>(&sIl[idx]) = l4;
        float4 vj = *reinterpret_cast<const float4*>(Xb + (long)(j0 + r) * DD + c * 4);
        cvt4(vj, h4, l4);
        *reinterpret_cast<ushort4*>(&sJh[idx]) = h4;
        *reinterpret_cast<ushort4*>(&sJl[idx]) = l4;
    }
    __syncthreads();

    f32x4 acc[2][2];
#pragma unroll
    for (int m = 0; m < 2; ++m)
#pragma unroll
        for (int n = 0; n < 2; ++n) acc[m][n] = f32x4{0.f, 0.f, 0.f, 0.f};

#pragma unroll
    for (int c2 = 0; c2 < 2; ++c2) {
        const int oct = c2 * 4 + lg;
        bf16x8 a_h[2], a_l[2], b_h[2], b_l[2];
#pragma unroll
        for (int m = 0; m < 2; ++m) {
            int row = wr * 32 + m * 16 + lr;
            a_h[m] = ld_bf8(&sIh[swzR(row, oct)]);
            a_l[m] = ld_bf8(&sIl[swzR(row, oct)]);
            int col = wc * 32 + m * 16 + lr;
            b_h[m] = ld_bf8(&sJh[swzR(col, oct)]);
            b_l[m] = ld_bf8(&sJl[swzR(col, oct)]);
        }
#pragma unroll
        for (int m = 0; m < 2; ++m)
#pragma unroll
            for (int n = 0; n < 2; ++n) {
                acc[m][n] = mfma16(a_h[m], b_h[n], acc[m][n]);
                acc[m][n] = mfma16(a_h[m], b_l[n], acc[m][n]);
                acc[m][n] = mfma16(a_l[m], b_h[n], acc[m][n]);
            }
    }

    float* __restrict__ AEb = AE + (long)b * NN * NN;
#pragma unroll
    for (int m = 0; m < 2; ++m) {
        const int ib = i0 + wr * 32 + m * 16 + lg * 4;
#pragma unroll
        for (int n = 0; n < 2; ++n) {
            const int jc = j0 + wc * 32 + n * 16 + lr;
#pragma unroll
            for (int jj = 0; jj < 4; ++jj) {
                float v = fmaxf(acc[m][n][jj], 0.f);
                if (ib + jj == jc) v = 0.f;
                AEb[(long)(ib + jj) * NN + jc] = v;
            }
        }
    }
}

// ---------------------------------------------------------------------------
// LayerNorm over [N,D] + relu + mean/max pool (R17-exact).
// ---------------------------------------------------------------------------
__global__ __launch_bounds__(256) void ln_pool(
    const float* __restrict__ pre, const float* __restrict__ gamma,
    const float* __restrict__ beta, float* __restrict__ h,
    float* __restrict__ zfeat, int zoff)
{
    const int b = blockIdx.x;
    const float* __restrict__ p = pre + (long)b * ND;
    const int t = threadIdx.x;

    float s = 0.f, s2 = 0.f;
    for (int i = t * 4; i < ND; i += 1024) {
        float4 v = *reinterpret_cast<const float4*>(p + i);
        s  += v.x + v.y + v.z + v.w;
        s2 += v.x * v.x + v.y * v.y + v.z * v.z + v.w * v.w;
    }
#pragma unroll
    for (int off = 32; off > 0; off >>= 1) {
        s  += __shfl_down(s, off, 64);
        s2 += __shfl_down(s2, off, 64);
    }
    __shared__ float red[8];
    if ((t & 63) == 0) { red[(t >> 6) * 2] = s; red[(t >> 6) * 2 + 1] = s2; }
    __syncthreads();
    __shared__ float mu_s, rstd_s;
    if (t == 0) {
        float ts  = red[0] + red[2] + red[4] + red[6];
        float ts2 = red[1] + red[3] + red[5] + red[7];
        float mu  = ts * (1.f / ND);
        float var = ts2 * (1.f / ND) - mu * mu;
        mu_s = mu; rstd_s = rsqrtf(var + 1e-5f);
    }
    __syncthreads();
    const float mu = mu_s, rstd = rstd_s;

    const int f4 = (t & 15) * 4, nt = t >> 4;
    float sum4[4] = {0.f, 0.f, 0.f, 0.f};
    float max4[4] = {0.f, 0.f, 0.f, 0.f};
    for (int n = nt; n < NN; n += 16) {
        float4 g4 = *reinterpret_cast<const float4*>(gamma + (long)n * DD + f4);
        float4 be = *reinterpret_cast<const float4*>(beta  + (long)n * DD + f4);
        float4 v;
        v.x = fmaxf((p[(long)(f4 + 0) * NN + n] - mu) * rstd * g4.x + be.x, 0.f);
        v.y = fmaxf((p[(long)(f4 + 1) * NN + n] - mu) * rstd * g4.y + be.y, 0.f);
        v.z = fmaxf((p[(long)(f4 + 2) * NN + n] - mu) * rstd * g4.z + be.z, 0.f);
        v.w = fmaxf((p[(long)(f4 + 3) * NN + n] - mu) * rstd * g4.w + be.w, 0.f);
        *reinterpret_cast<float4*>(h + (long)b * ND + (long)n * DD + f4) = v;
        sum4[0] += v.x; sum4[1] += v.y; sum4[2] += v.z; sum4[3] += v.w;
        max4[0] = fmaxf(max4[0], v.x); max4[1] = fmaxf(max4[1], v.y);
        max4[2] = fmaxf(max4[2], v.z); max4[3] = fmaxf(max4[3], v.w);
    }
    __shared__ float rs[16][64], rm[16][64];
#pragma unroll
    for (int j = 0; j < 4; ++j) { rs[nt][f4 + j] = sum4[j]; rm[nt][f4 + j] = max4[j]; }
    __syncthreads();
    if (t < 64) {
        float ss = 0.f, mm = 0.f;
#pragma unroll
        for (int k = 0; k < 16; ++k) { ss += rs[k][t]; mm = fmaxf(mm, rm[k][t]); }
        zfeat[b * 256 + zoff + t]      = ss * (1.f / NN);
        zfeat[b * 256 + zoff + 64 + t] = mm;
    }
}

// ---------------------------------------------------------------------------
// W[z][kdim][64] fp32 -> hi/lo bf16 planes [z][64][kdim]
// ---------------------------------------------------------------------------
__global__ void transW_split(const float* __restrict__ W,
                             unsigned short* __restrict__ Wh,
                             unsigned short* __restrict__ Wl,
                             int kdim, int total)
{
    int o = blockIdx.x * 256 + threadIdx.x;
    if (o >= total) return;
    int per = 64 * kdim;
    int zz = o / per, r = o % per;
    int f = r / kdim, k = r % kdim;
    float x = W[((long)zz * kdim + k) * 64 + f];
    __bf16 hb = (__bf16)x;
    __bf16 lb = (__bf16)(x - (float)hb);
    Wh[o] = __builtin_bit_cast(unsigned short, hb);
    Wl[o] = __builtin_bit_cast(unsigned short, lb);
}

// ---------------------------------------------------------------------------
// Tiny MLP heads (R17-exact).
// ---------------------------------------------------------------------------
__global__ __launch_bounds__(64) void heads(
    const float* __restrict__ zfeat,
    const float* __restrict__ p1w, const float* __restrict__ p1b,
    const float* __restrict__ p2w, const float* __restrict__ p2b,
    const float* __restrict__ p3w, const float* __restrict__ p3b,
    const float* __restrict__ s1w, const float* __restrict__ s1b,
    const float* __restrict__ s2w, const float* __restrict__ s2b,
    const float* __restrict__ p4w, const float* __restrict__ p4b,
    float* __restrict__ outc, float* __restrict__ outs)
{
    const int b = blockIdx.x, t = threadIdx.x;
    __shared__ float zf[256], v1[64], v2[64], lg[2];
    for (int i = t; i < 256; i += 64) zf[i] = zfeat[b * 256 + i];
    __syncthreads();

    float a = p1b[t];
    for (int z = 0; z < 256; ++z) a = fmaf(zf[z], p1w[z * 64 + t], a);
    v1[t] = a >= 0.f ? a : 0.2f * a;
    __syncthreads();
    float a2 = p2b[t];
    for (int z = 0; z < 64; ++z) a2 = fmaf(v1[z], p2w[z * 64 + t], a2);
    v2[t] = a2 >= 0.f ? a2 : 0.2f * a2;
    __syncthreads();
    if (t < 4) {
        float a3 = p3b[t];
        for (int z = 0; z < 64; ++z) a3 = fmaf(v2[z], p3w[z * 4 + t], a3);
        outc[b * 4 + t] = 1.f / (1.f + expf(-a3));
    }
    __syncthreads();

    float c = s1b[t];
    for (int z = 0; z < 256; ++z) c = fmaf(zf[z], s1w[z * 64 + t], c);
    v1[t] = c >= 0.f ? c : 0.2f * c;
    __syncthreads();
    float c2 = s2b[t];
    for (int z = 0; z < 64; ++z) c2 = fmaf(v1[z], s2w[z * 64 + t], c2);
    v2[t] = c2 >= 0.f ? c2 : 0.2f * c2;
    __syncthreads();
    if (t < 2) {
        float d = p4b[t];
        for (int z = 0; z < 64; ++z) d = fmaf(v2[z], p4w[z * 2 + t], d);
        lg[t] = d;
    }
    __syncthreads();
    if (t < 2) {
        float m = fmaxf(lg[0], lg[1]);
        float lse = m + logf(expf(lg[0] - m) + expf(lg[1] - m));
        outs[b * 2 + t] = lg[t] - lse;
    }
}

// ---------------------------------------------------------------------------
// Orchestration (R17-exact except cheb grid 1024).
// ---------------------------------------------------------------------------
extern "C" void kernel_launch(void* const* d_in, const int* in_sizes, int n_in,
                              void* d_out, int out_size, void* d_ws, size_t ws_size,
                              hipStream_t stream)
{
    const float* A   = (const float*)d_in[0];
    const float* X   = (const float*)d_in[1];
    const float* W1  = (const float*)d_in[2];
    const float* b1v = (const float*)d_in[3];
    const float* W2  = (const float*)d_in[4];
    const float* b2v = (const float*)d_in[5];
    const float* W3  = (const float*)d_in[6];
    const float* b3v = (const float*)d_in[7];
    const float* g1  = (const float*)d_in[8];
    const float* bt1 = (const float*)d_in[9];
    const float* g2  = (const float*)d_in[10];
    const float* bt2 = (const float*)d_in[11];
    const float* p1w = (const float*)d_in[12];
    const float* p1b = (const float*)d_in[13];
    const float* p2w = (const float*)d_in[14];
    const float* p2b = (const float*)d_in[15];
    const float* p3w = (const float*)d_in[16];
    const float* p3b = (const float*)d_in[17];
    const float* s1w = (const float*)d_in[18];
    const float* s1b = (const float*)d_in[19];
    const float* s2w = (const float*)d_in[20];
    const float* s2b = (const float*)d_in[21];
    const float* p4w = (const float*)d_in[22];
    const float* p4b = (const float*)d_in[23];

    float* out   = (float*)d_out;
    float* Zs    = out;
    float* bufA  = out + 6 * BND;
    float* bufB  = out + 7 * BND;
    float* ws    = (float*)d_ws;
    float* bufC  = ws;
    float* hbuf  = ws + BND;
    float* zfeat = ws + 2 * BND;
    unsigned short* w1h = (unsigned short*)(zfeat + 16384);
    unsigned short* w1l = w1h + 6 * NN * DD;
    unsigned short* w2h = w1l + 6 * NN * DD;
    unsigned short* w2l = w2h + 6 * DD * DD;
    unsigned short* w3h = w2l + 6 * DD * DD;
    unsigned short* w3l = w3h + 6 * DD * DD;
    float* outc  = out + (long)BB * NN * NN;
    float* outsc = outc + BB * 4;

    const dim3 blk(256), gblk(512);
    const long ABATCH = (long)NN * NN;

    transW_split<<<dim3((6 * NN * DD + 255) / 256), blk, 0, stream>>>(W1, w1h, w1l, NN, 6 * NN * DD);
    transW_split<<<dim3((6 * DD * DD + 255) / 256), blk, 0, stream>>>(W2, w2h, w2l, DD, 6 * DD * DD);
    transW_split<<<dim3((6 * DD * DD + 255) / 256), blk, 0, stream>>>(W3, w3h, w3l, DD, 6 * DD * DD);

    const dim3 gridZ(8 * 64 * 2);    // z-triple fused: 1024 blocks
    const dim3 gridC(16 * 64);       // cheb half-tile: 1024 blocks

    auto cheb = [&](const float* bias, float* xout, bool rowOut) {
        gemm_mfma<false, true, false, false><<<gridC, gblk, 0, stream>>>(
            A, NN, ABATCH, Zs + 5 * BND, (long)ND, nullptr, Zs + 4 * BND, nullptr,
            2.f, 0.f, NN, bufA);
        gemm_mfma<true, true, false, false><<<gridC, gblk, 0, stream>>>(
            A, NN, ABATCH, bufA, (long)ND, Zs + 5 * BND, Zs + 3 * BND, nullptr,
            2.f, -1.f, NN, bufB);
        gemm_mfma<true, true, false, false><<<gridC, gblk, 0, stream>>>(
            A, NN, ABATCH, bufB, (long)ND, bufA, Zs + 2 * BND, nullptr,
            2.f, -1.f, NN, bufC);
        gemm_mfma<true, true, false, false><<<gridC, gblk, 0, stream>>>(
            A, NN, ABATCH, bufC, (long)ND, bufB, Zs + 1 * BND, nullptr,
            2.f, -1.f, NN, bufA);
        if (rowOut)
            gemm_mfma<true, true, true, true><<<gridC, gblk, 0, stream>>>(
                A, NN, ABATCH, bufA, (long)ND, bufC, Zs + 0 * BND, bias,
                1.f, -1.f, NN, xout);
        else
            gemm_mfma<true, true, true, false><<<gridC, gblk, 0, stream>>>(
                A, NN, ABATCH, bufA, (long)ND, bufC, Zs + 0 * BND, bias,
                1.f, -1.f, NN, xout);
    };

    // stage 1
    gemm_z3<<<gridZ, gblk, 0, stream>>>(X, NN, ABATCH, w1h, w1l, NN, Zs, BND);
    cheb(b1v, bufB, false);
    ln_pool<<<dim3(64), blk, 0, stream>>>(bufB, g1, bt1, hbuf, zfeat, 0);

    // stage 2
    gemm_z3<<<gridZ, gblk, 0, stream>>>(hbuf, DD, (long)ND, w2h, w2l, DD, Zs, BND);
    cheb(b2v, bufB, false);
    ln_pool<<<dim3(64), blk, 0, stream>>>(bufB, g2, bt2, hbuf, zfeat, 128);

    // stage 3
    gemm_z3<<<gridZ, gblk, 0, stream>>>(hbuf, DD, (long)ND, w3h, w3l, DD, Zs, BND);
    cheb(b3v, hbuf, true);

    // AE = relu(X0 X0^T), zero diag
    outer_v18<<<dim3(8, 8, 64), blk, 0, stream>>>(hbuf, out);

    // heads
    heads<<<dim3(64), dim3(64), 0, stream>>>(
        zfeat, p1w, p1b, p2w, p2b, p3w, p3b, s1w, s1b, s2w, s2b, p4w, p4b, outc, outsc);
}

// Round 19
// 437.410 us; speedup vs baseline: 1.0762x; 1.0762x over previous
//
#include <hip/hip_runtime.h>

#define NN 512
#define DD 64
#define BB 64
#define ND (NN * DD)          // 32768

static const long BND = (long)BB * ND;   // 2,097,152

typedef __bf16 bf16x8 __attribute__((ext_vector_type(8)));
typedef float  f32x4  __attribute__((ext_vector_type(4)));

__device__ __forceinline__ float bf2f(unsigned short u) {
    return __uint_as_float(((unsigned int)u) << 16);
}
// fp32 -> hi/lo bf16 split via native casts (HW v_cvt_pk_bf16_f32, RNE)
__device__ __forceinline__ void cvt4(const float4& x, ushort4& h, ushort4& l) {
    __bf16 h0 = (__bf16)x.x, h1 = (__bf16)x.y, h2 = (__bf16)x.z, h3 = (__bf16)x.w;
    __bf16 l0 = (__bf16)(x.x - (float)h0);
    __bf16 l1 = (__bf16)(x.y - (float)h1);
    __bf16 l2 = (__bf16)(x.z - (float)h2);
    __bf16 l3 = (__bf16)(x.w - (float)h3);
    h = make_ushort4(__builtin_bit_cast(unsigned short, h0),
                     __builtin_bit_cast(unsigned short, h1),
                     __builtin_bit_cast(unsigned short, h2),
                     __builtin_bit_cast(unsigned short, h3));
    l = make_ushort4(__builtin_bit_cast(unsigned short, l0),
                     __builtin_bit_cast(unsigned short, l1),
                     __builtin_bit_cast(unsigned short, l2),
                     __builtin_bit_cast(unsigned short, l3));
}
__device__ __forceinline__ bf16x8 ld_bf8(const unsigned short* p) {
    int4 v = *reinterpret_cast<const int4*>(p);
    return __builtin_bit_cast(bf16x8, v);
}
__device__ __forceinline__ f32x4 mfma16(bf16x8 a, bf16x8 b, f32x4 c) {
    return __builtin_amdgcn_mfma_f32_16x16x32_bf16(a, b, c, 0, 0, 0);
}
// LDS tile [64 r][64 shorts], XOR swizzle (0 bank conflicts, R2-proven)
__device__ __forceinline__ int swzW4(int r, int c) {   // c = ushort4 group 0..15
    return r * 64 + (((c >> 1) ^ (r & 7)) << 3) + ((c & 1) << 2);
}
__device__ __forceinline__ int swzR(int r, int oct) {  // oct 0..7
    return r * 64 + ((oct ^ (r & 7)) << 3);
}

// ---------------------------------------------------------------------------
// gemm_z3: Z-GEMM, z-TRIPLE fused.  out[b,z,i,f] = sum_k A[b,i,k]*W[z][f,k]
// for z = zp*3 + {0,1,2}.  X cvt-staged once per triple; W from pre-split
// planes via named-int4 register->LDS copy (zero cvt).  512 thr, 8 waves x
// 16x32 per z, 2 barriers/step, XCD-chunked 1D grid.  LDS 64 KB.
// ---------------------------------------------------------------------------
__global__ __launch_bounds__(512) void gemm_z3(
    const float* __restrict__ Afp, int lda, long aBatch,
    const unsigned short* __restrict__ Wh, const unsigned short* __restrict__ Wl,
    int kdim, float* __restrict__ out, long outZ)
{
    const int nwg = gridDim.x;
    const int lid = (blockIdx.x & 7) * (nwg >> 3) + (blockIdx.x >> 3);
    const int zp  = lid & 1;                 // 2 z-triples
    const int t2  = lid >> 1;
    const int i0  = (t2 & 7) << 6;
    const int b   = t2 >> 3;

    const float* __restrict__ Ab = Afp + (long)b * aBatch;
    const unsigned short* __restrict__ W0h = Wh + (long)(zp * 3 + 0) * 64 * kdim;
    const unsigned short* __restrict__ W0l = Wl + (long)(zp * 3 + 0) * 64 * kdim;
    const unsigned short* __restrict__ W1h = Wh + (long)(zp * 3 + 1) * 64 * kdim;
    const unsigned short* __restrict__ W1l = Wl + (long)(zp * 3 + 1) * 64 * kdim;
    const unsigned short* __restrict__ W2h = Wh + (long)(zp * 3 + 2) * 64 * kdim;
    const unsigned short* __restrict__ W2l = Wl + (long)(zp * 3 + 2) * 64 * kdim;

    __shared__ __align__(16) unsigned short sXh[4096];
    __shared__ __align__(16) unsigned short sXl[4096];
    __shared__ __align__(16) unsigned short sW0h[4096];
    __shared__ __align__(16) unsigned short sW0l[4096];
    __shared__ __align__(16) unsigned short sW1h[4096];
    __shared__ __align__(16) unsigned short sW1l[4096];
    __shared__ __align__(16) unsigned short sW2h[4096];
    __shared__ __align__(16) unsigned short sW2l[4096];

    const int t = threadIdx.x;
    const int w = t >> 6, lane = t & 63;
    const int wr = w >> 1, wc = w & 1;
    const int lr = lane & 15, lg = lane >> 4;

    f32x4 acc[3][2];
#pragma unroll
    for (int zz = 0; zz < 3; ++zz)
#pragma unroll
        for (int n = 0; n < 2; ++n) acc[zz][n] = f32x4{0.f, 0.f, 0.f, 0.f};

    const int steps = kdim >> 6;
    const int rW = t >> 3, jW = t & 7;
    const int widx = rW * 64 + ((jW ^ (rW & 7)) << 3);
    const long wsrc0 = (long)rW * kdim + jW * 8;

    float4 ra[2];
    int4 w0h, w0l, w1h, w1l, w2h, w2l;       // named (rule #20)

#pragma unroll
    for (int l = 0; l < 2; ++l) {
        int q = t + l * 512, r = q >> 4, c = q & 15;
        ra[l] = *reinterpret_cast<const float4*>(Ab + (long)(i0 + r) * lda + c * 4);
    }
    w0h = *reinterpret_cast<const int4*>(W0h + wsrc0);
    w0l = *reinterpret_cast<const int4*>(W0l + wsrc0);
    w1h = *reinterpret_cast<const int4*>(W1h + wsrc0);
    w1l = *reinterpret_cast<const int4*>(W1l + wsrc0);
    w2h = *reinterpret_cast<const int4*>(W2h + wsrc0);
    w2l = *reinterpret_cast<const int4*>(W2l + wsrc0);

    for (int s = 0; s < steps; ++s) {
        if (s) __syncthreads();
#pragma unroll
        for (int l = 0; l < 2; ++l) {
            int q = t + l * 512, r = q >> 4, c = q & 15;
            int idx = swzW4(r, c);
            ushort4 h4, l4;
            cvt4(ra[l], h4, l4);
            *reinterpret_cast<ushort4*>(&sXh[idx]) = h4;
            *reinterpret_cast<ushort4*>(&sXl[idx]) = l4;
        }
        *reinterpret_cast<int4*>(&sW0h[widx]) = w0h;
        *reinterpret_cast<int4*>(&sW0l[widx]) = w0l;
        *reinterpret_cast<int4*>(&sW1h[widx]) = w1h;
        *reinterpret_cast<int4*>(&sW1l[widx]) = w1l;
        *reinterpret_cast<int4*>(&sW2h[widx]) = w2h;
        *reinterpret_cast<int4*>(&sW2l[widx]) = w2l;
        __syncthreads();
        if (s + 1 < steps) {
            const int k0n = (s + 1) << 6;
#pragma unroll
            for (int l = 0; l < 2; ++l) {
                int q = t + l * 512, r = q >> 4, c = q & 15;
                ra[l] = *reinterpret_cast<const float4*>(Ab + (long)(i0 + r) * lda + k0n + c * 4);
            }
            w0h = *reinterpret_cast<const int4*>(W0h + wsrc0 + k0n);
            w0l = *reinterpret_cast<const int4*>(W0l + wsrc0 + k0n);
            w1h = *reinterpret_cast<const int4*>(W1h + wsrc0 + k0n);
            w1l = *reinterpret_cast<const int4*>(W1l + wsrc0 + k0n);
            w2h = *reinterpret_cast<const int4*>(W2h + wsrc0 + k0n);
            w2l = *reinterpret_cast<const int4*>(W2l + wsrc0 + k0n);
        }
#pragma unroll
        for (int c2 = 0; c2 < 2; ++c2) {
            const int oct = c2 * 4 + lg;
            const int arow = wr * 16 + lr;
            bf16x8 a_h = ld_bf8(&sXh[swzR(arow, oct)]);
            bf16x8 a_l = ld_bf8(&sXl[swzR(arow, oct)]);
#pragma unroll
            for (int n = 0; n < 2; ++n) {
                const int col = wc * 32 + n * 16 + lr;
                const int ci = swzR(col, oct);
                bf16x8 b0h = ld_bf8(&sW0h[ci]);
                bf16x8 b0l = ld_bf8(&sW0l[ci]);
                acc[0][n] = mfma16(a_h, b0h, acc[0][n]);
                acc[0][n] = mfma16(a_h, b0l, acc[0][n]);
                acc[0][n] = mfma16(a_l, b0h, acc[0][n]);
                bf16x8 b1h = ld_bf8(&sW1h[ci]);
                bf16x8 b1l = ld_bf8(&sW1l[ci]);
                acc[1][n] = mfma16(a_h, b1h, acc[1][n]);
                acc[1][n] = mfma16(a_h, b1l, acc[1][n]);
                acc[1][n] = mfma16(a_l, b1h, acc[1][n]);
                bf16x8 b2h = ld_bf8(&sW2h[ci]);
                bf16x8 b2l = ld_bf8(&sW2l[ci]);
                acc[2][n] = mfma16(a_h, b2h, acc[2][n]);
                acc[2][n] = mfma16(a_h, b2l, acc[2][n]);
                acc[2][n] = mfma16(a_l, b2h, acc[2][n]);
            }
        }
    }

    const long cOff = (long)b * ND;
    const int nb = i0 + wr * 16 + lg * 4;
#pragma unroll
    for (int zz = 0; zz < 3; ++zz) {
        const long oOff = (long)(zp * 3 + zz) * outZ + cOff;
#pragma unroll
        for (int n = 0; n < 2; ++n) {
            const int f = wc * 32 + n * 16 + lr;
            float4 v;
            v.x = acc[zz][n][0]; v.y = acc[zz][n][1];
            v.z = acc[zz][n][2]; v.w = acc[zz][n][3];
            *reinterpret_cast<float4*>(out + oOff + (long)f * NN + nb) = v;
        }
    }
}

// ---------------------------------------------------------------------------
// cheb GEMM (R15/R17-exact: 64x64 tile, single-buffer, 2 barriers/step,
// XCD-chunked).
// ---------------------------------------------------------------------------
template <bool HAS_VM, bool HAS_Z, bool HAS_BIAS, bool OUT_ROW>
__global__ __launch_bounds__(512) void gemm_mfma(
    const float* __restrict__ A, int lda, long aBatch,
    const float* __restrict__ U, long uBatch, long uZ,
    const float* __restrict__ Vm, const float* __restrict__ Zt,
    const float* __restrict__ bias, float alpha, float beta, int kdim,
    float* __restrict__ out, long outZ, int nz)
{
    const int nwg = gridDim.x;
    const int lid = (blockIdx.x & 7) * (nwg >> 3) + (blockIdx.x >> 3);
    const int z   = lid % nz;
    const int t2  = lid / nz;
    const int i0  = (t2 & 7) << 6;
    const int b   = t2 >> 3;

    const float* __restrict__ Ab = A + (long)b * aBatch;
    const float* __restrict__ Ub = U + (long)b * uBatch + (long)z * uZ;

    __shared__ __align__(16) unsigned short sAh[4096];
    __shared__ __align__(16) unsigned short sAl[4096];
    __shared__ __align__(16) unsigned short sBh[4096];
    __shared__ __align__(16) unsigned short sBl[4096];

    const int t = threadIdx.x;
    const int w = t >> 6, lane = t & 63;
    const int wr = w >> 1, wc = w & 1;
    const int lr = lane & 15, lg = lane >> 4;

    f32x4 acc[2];
    acc[0] = f32x4{0.f, 0.f, 0.f, 0.f};
    acc[1] = f32x4{0.f, 0.f, 0.f, 0.f};

    const int steps = kdim >> 6;
    float4 ra[2], rb[2];

#pragma unroll
    for (int l = 0; l < 2; ++l) {
        int q = t + l * 512, r = q >> 4, c = q & 15;
        ra[l] = *reinterpret_cast<const float4*>(Ab + (long)(i0 + r) * lda + c * 4);
        rb[l] = *reinterpret_cast<const float4*>(Ub + (long)r * kdim + c * 4);
    }

    for (int s = 0; s < steps; ++s) {
        if (s) __syncthreads();
#pragma unroll
        for (int l = 0; l < 2; ++l) {
            int q = t + l * 512, r = q >> 4, c = q & 15;
            int idx = swzW4(r, c);
            ushort4 h4, l4;
            cvt4(ra[l], h4, l4);
            *reinterpret_cast<ushort4*>(&sAh[idx]) = h4;
            *reinterpret_cast<ushort4*>(&sAl[idx]) = l4;
            cvt4(rb[l], h4, l4);
            *reinterpret_cast<ushort4*>(&sBh[idx]) = h4;
            *reinterpret_cast<ushort4*>(&sBl[idx]) = l4;
        }
        __syncthreads();
        if (s + 1 < steps) {
            const int k0n = (s + 1) << 6;
#pragma unroll
            for (int l = 0; l < 2; ++l) {
                int q = t + l * 512, r = q >> 4, c = q & 15;
                ra[l] = *reinterpret_cast<const float4*>(Ab + (long)(i0 + r) * lda + k0n + c * 4);
                rb[l] = *reinterpret_cast<const float4*>(Ub + (long)r * kdim + k0n + c * 4);
            }
        }
#pragma unroll
        for (int c2 = 0; c2 < 2; ++c2) {
            const int oct = c2 * 4 + lg;
            const int arow = wr * 16 + lr;
            bf16x8 a_h = ld_bf8(&sAh[swzR(arow, oct)]);
            bf16x8 a_l = ld_bf8(&sAl[swzR(arow, oct)]);
            bf16x8 b_h[2], b_l[2];
#pragma unroll
            for (int n = 0; n < 2; ++n) {
                int col = wc * 32 + n * 16 + lr;
                b_h[n] = ld_bf8(&sBh[swzR(col, oct)]);
                b_l[n] = ld_bf8(&sBl[swzR(col, oct)]);
            }
#pragma unroll
            for (int n = 0; n < 2; ++n) {
                acc[n] = mfma16(a_h, b_h[n], acc[n]);
                acc[n] = mfma16(a_h, b_l[n], acc[n]);
                acc[n] = mfma16(a_l, b_h[n], acc[n]);
            }
        }
    }

    const long cOff = (long)b * ND;
    const long oOff = (long)z * outZ + cOff;
    const int nb = i0 + wr * 16 + lg * 4;
#pragma unroll
    for (int n = 0; n < 2; ++n) {
        const int f = wc * 32 + n * 16 + lr;
        float4 v;
        v.x = alpha * acc[n][0]; v.y = alpha * acc[n][1];
        v.z = alpha * acc[n][2]; v.w = alpha * acc[n][3];
        if (HAS_VM) {
            float4 mv = *reinterpret_cast<const float4*>(Vm + cOff + (long)f * NN + nb);
            v.x += beta * mv.x; v.y += beta * mv.y; v.z += beta * mv.z; v.w += beta * mv.w;
        }
        if (HAS_Z) {
            float4 zz = *reinterpret_cast<const float4*>(Zt + cOff + (long)f * NN + nb);
            v.x += zz.x; v.y += zz.y; v.z += zz.z; v.w += zz.w;
        }
        if (HAS_BIAS) {
            float bf = bias[f];
            v.x += bf; v.y += bf; v.z += bf; v.w += bf;
        }
        if (OUT_ROW) {
            float* __restrict__ outb = out + cOff;
            outb[(long)(nb + 0) * DD + f] = v.x;
            outb[(long)(nb + 1) * DD + f] = v.y;
            outb[(long)(nb + 2) * DD + f] = v.z;
            outb[(long)(nb + 3) * DD + f] = v.w;
        } else {
            *reinterpret_cast<float4*>(out + oOff + (long)f * NN + nb) = v;
        }
    }
}

// ---------------------------------------------------------------------------
// AE = relu(X0 X0^T), diag zeroed (R17-exact). X0 fp32 row-major [512][64].
// ---------------------------------------------------------------------------
__global__ __launch_bounds__(256) void outer_v19(
    const float* __restrict__ X0, float* __restrict__ AE)
{
    const int b = blockIdx.z;
    const int j0 = blockIdx.x * 64, i0 = blockIdx.y * 64;
    const float* __restrict__ Xb = X0 + (long)b * ND;

    __shared__ __align__(16) unsigned short sIh[4096];
    __shared__ __align__(16) unsigned short sIl[4096];
    __shared__ __align__(16) unsigned short sJh[4096];
    __shared__ __align__(16) unsigned short sJl[4096];

    const int t = threadIdx.x;
    const int w = t >> 6, lane = t & 63;
    const int wr = w >> 1, wc = w & 1;
    const int lr = lane & 15, lg = lane >> 4;

#pragma unroll
    for (int l = 0; l < 4; ++l) {
        int q = t + l * 256;
        int r = q >> 4, c = q & 15;
        int idx = swzW4(r, c);
        ushort4 h4, l4;
        float4 vi = *reinterpret_cast<const float4*>(Xb + (long)(i0 + r) * DD + c * 4);
        cvt4(vi, h4, l4);
        *reinterpret_cast<ushort4*>(&sIh[idx]) = h4;
        *reinterpret_cast<ushort4*>(&sIl[idx]) = l4;
        float4 vj = *reinterpret_cast<const float4*>(Xb + (long)(j0 + r) * DD + c * 4);
        cvt4(vj, h4, l4);
        *reinterpret_cast<ushort4*>(&sJh[idx]) = h4;
        *reinterpret_cast<ushort4*>(&sJl[idx]) = l4;
    }
    __syncthreads();

    f32x4 acc[2][2];
#pragma unroll
    for (int m = 0; m < 2; ++m)
#pragma unroll
        for (int n = 0; n < 2; ++n) acc[m][n] = f32x4{0.f, 0.f, 0.f, 0.f};

#pragma unroll
    for (int c2 = 0; c2 < 2; ++c2) {
        const int oct = c2 * 4 + lg;
        bf16x8 a_h[2], a_l[2], b_h[2], b_l[2];
#pragma unroll
        for (int m = 0; m < 2; ++m) {
            int row = wr * 32 + m * 16 + lr;
            a_h[m] = ld_bf8(&sIh[swzR(row, oct)]);
            a_l[m] = ld_bf8(&sIl[swzR(row, oct)]);
            int col = wc * 32 + m * 16 + lr;
            b_h[m] = ld_bf8(&sJh[swzR(col, oct)]);
            b_l[m] = ld_bf8(&sJl[swzR(col, oct)]);
        }
#pragma unroll
        for (int m = 0; m < 2; ++m)
#pragma unroll
            for (int n = 0; n < 2; ++n) {
                acc[m][n] = mfma16(a_h[m], b_h[n], acc[m][n]);
                acc[m][n] = mfma16(a_h[m], b_l[n], acc[m][n]);
                acc[m][n] = mfma16(a_l[m], b_h[n], acc[m][n]);
            }
    }

    float* __restrict__ AEb = AE + (long)b * NN * NN;
#pragma unroll
    for (int m = 0; m < 2; ++m) {
        const int ib = i0 + wr * 32 + m * 16 + lg * 4;
#pragma unroll
        for (int n = 0; n < 2; ++n) {
            const int jc = j0 + wc * 32 + n * 16 + lr;
#pragma unroll
            for (int jj = 0; jj < 4; ++jj) {
                float v = fmaxf(acc[m][n][jj], 0.f);
                if (ib + jj == jc) v = 0.f;
                AEb[(long)(ib + jj) * NN + jc] = v;
            }
        }
    }
}

// ---------------------------------------------------------------------------
// LayerNorm over [N,D] + relu + mean/max pool (R17-exact).
// ---------------------------------------------------------------------------
__global__ __launch_bounds__(256) void ln_pool(
    const float* __restrict__ pre, const float* __restrict__ gamma,
    const float* __restrict__ beta, float* __restrict__ h,
    float* __restrict__ zfeat, int zoff)
{
    const int b = blockIdx.x;
    const float* __restrict__ p = pre + (long)b * ND;
    const int t = threadIdx.x;

    float s = 0.f, s2 = 0.f;
    for (int i = t * 4; i < ND; i += 1024) {
        float4 v = *reinterpret_cast<const float4*>(p + i);
        s  += v.x + v.y + v.z + v.w;
        s2 += v.x * v.x + v.y * v.y + v.z * v.z + v.w * v.w;
    }
#pragma unroll
    for (int off = 32; off > 0; off >>= 1) {
        s  += __shfl_down(s, off, 64);
        s2 += __shfl_down(s2, off, 64);
    }
    __shared__ float red[8];
    if ((t & 63) == 0) { red[(t >> 6) * 2] = s; red[(t >> 6) * 2 + 1] = s2; }
    __syncthreads();
    __shared__ float mu_s, rstd_s;
    if (t == 0) {
        float ts  = red[0] + red[2] + red[4] + red[6];
        float ts2 = red[1] + red[3] + red[5] + red[7];
        float mu  = ts * (1.f / ND);
        float var = ts2 * (1.f / ND) - mu * mu;
        mu_s = mu; rstd_s = rsqrtf(var + 1e-5f);
    }
    __syncthreads();
    const float mu = mu_s, rstd = rstd_s;

    const int f4 = (t & 15) * 4, nt = t >> 4;
    float sum4[4] = {0.f, 0.f, 0.f, 0.f};
    float max4[4] = {0.f, 0.f, 0.f, 0.f};
    for (int n = nt; n < NN; n += 16) {
        float4 g4 = *reinterpret_cast<const float4*>(gamma + (long)n * DD + f4);
        float4 be = *reinterpret_cast<const float4*>(beta  + (long)n * DD + f4);
        float4 v;
        v.x = fmaxf((p[(long)(f4 + 0) * NN + n] - mu) * rstd * g4.x + be.x, 0.f);
        v.y = fmaxf((p[(long)(f4 + 1) * NN + n] - mu) * rstd * g4.y + be.y, 0.f);
        v.z = fmaxf((p[(long)(f4 + 2) * NN + n] - mu) * rstd * g4.z + be.z, 0.f);
        v.w = fmaxf((p[(long)(f4 + 3) * NN + n] - mu) * rstd * g4.w + be.w, 0.f);
        *reinterpret_cast<float4*>(h + (long)b * ND + (long)n * DD + f4) = v;
        sum4[0] += v.x; sum4[1] += v.y; sum4[2] += v.z; sum4[3] += v.w;
        max4[0] = fmaxf(max4[0], v.x); max4[1] = fmaxf(max4[1], v.y);
        max4[2] = fmaxf(max4[2], v.z); max4[3] = fmaxf(max4[3], v.w);
    }
    __shared__ float rs[16][64], rm[16][64];
#pragma unroll
    for (int j = 0; j < 4; ++j) { rs[nt][f4 + j] = sum4[j]; rm[nt][f4 + j] = max4[j]; }
    __syncthreads();
    if (t < 64) {
        float ss = 0.f, mm = 0.f;
#pragma unroll
        for (int k = 0; k < 16; ++k) { ss += rs[k][t]; mm = fmaxf(mm, rm[k][t]); }
        zfeat[b * 256 + zoff + t]      = ss * (1.f / NN);
        zfeat[b * 256 + zoff + 64 + t] = mm;
    }
}

// ---------------------------------------------------------------------------
// W[z][kdim][64] fp32 -> hi/lo bf16 planes [z][64][kdim]
// ---------------------------------------------------------------------------
__global__ void transW_split(const float* __restrict__ W,
                             unsigned short* __restrict__ Wh,
                             unsigned short* __restrict__ Wl,
                             int kdim, int total)
{
    int o = blockIdx.x * 256 + threadIdx.x;
    if (o >= total) return;
    int per = 64 * kdim;
    int zz = o / per, r = o % per;
    int f = r / kdim, k = r % kdim;
    float x = W[((long)zz * kdim + k) * 64 + f];
    __bf16 hb = (__bf16)x;
    __bf16 lb = (__bf16)(x - (float)hb);
    Wh[o] = __builtin_bit_cast(unsigned short, hb);
    Wl[o] = __builtin_bit_cast(unsigned short, lb);
}

// ---------------------------------------------------------------------------
// Tiny MLP heads (R17-exact).
// ---------------------------------------------------------------------------
__global__ __launch_bounds__(64) void heads(
    const float* __restrict__ zfeat,
    const float* __restrict__ p1w, const float* __restrict__ p1b,
    const float* __restrict__ p2w, const float* __restrict__ p2b,
    const float* __restrict__ p3w, const float* __restrict__ p3b,
    const float* __restrict__ s1w, const float* __restrict__ s1b,
    const float* __restrict__ s2w, const float* __restrict__ s2b,
    const float* __restrict__ p4w, const float* __restrict__ p4b,
    float* __restrict__ outc, float* __restrict__ outs)
{
    const int b = blockIdx.x, t = threadIdx.x;
    __shared__ float zf[256], v1[64], v2[64], lg[2];
    for (int i = t; i < 256; i += 64) zf[i] = zfeat[b * 256 + i];
    __syncthreads();

    float a = p1b[t];
    for (int z = 0; z < 256; ++z) a = fmaf(zf[z], p1w[z * 64 + t], a);
    v1[t] = a >= 0.f ? a : 0.2f * a;
    __syncthreads();
    float a2 = p2b[t];
    for (int z = 0; z < 64; ++z) a2 = fmaf(v1[z], p2w[z * 64 + t], a2);
    v2[t] = a2 >= 0.f ? a2 : 0.2f * a2;
    __syncthreads();
    if (t < 4) {
        float a3 = p3b[t];
        for (int z = 0; z < 64; ++z) a3 = fmaf(v2[z], p3w[z * 4 + t], a3);
        outc[b * 4 + t] = 1.f / (1.f + expf(-a3));
    }
    __syncthreads();

    float c = s1b[t];
    for (int z = 0; z < 256; ++z) c = fmaf(zf[z], s1w[z * 64 + t], c);
    v1[t] = c >= 0.f ? c : 0.2f * c;
    __syncthreads();
    float c2 = s2b[t];
    for (int z = 0; z < 64; ++z) c2 = fmaf(v1[z], s2w[z * 64 + t], c2);
    v2[t] = c2 >= 0.f ? c2 : 0.2f * c2;
    __syncthreads();
    if (t < 2) {
        float d = p4b[t];
        for (int z = 0; z < 64; ++z) d = fmaf(v2[z], p4w[z * 2 + t], d);
        lg[t] = d;
    }
    __syncthreads();
    if (t < 2) {
        float m = fmaxf(lg[0], lg[1]);
        float lse = m + logf(expf(lg[0] - m) + expf(lg[1] - m));
        outs[b * 2 + t] = lg[t] - lse;
    }
}

// ---------------------------------------------------------------------------
// Orchestration (R17-exact).
// ---------------------------------------------------------------------------
extern "C" void kernel_launch(void* const* d_in, const int* in_sizes, int n_in,
                              void* d_out, int out_size, void* d_ws, size_t ws_size,
                              hipStream_t stream)
{
    const float* A   = (const float*)d_in[0];
    const float* X   = (const float*)d_in[1];
    const float* W1  = (const float*)d_in[2];
    const float* b1v = (const float*)d_in[3];
    const float* W2  = (const float*)d_in[4];
    const float* b2v = (const float*)d_in[5];
    const float* W3  = (const float*)d_in[6];
    const float* b3v = (const float*)d_in[7];
    const float* g1  = (const float*)d_in[8];
    const float* bt1 = (const float*)d_in[9];
    const float* g2  = (const float*)d_in[10];
    const float* bt2 = (const float*)d_in[11];
    const float* p1w = (const float*)d_in[12];
    const float* p1b = (const float*)d_in[13];
    const float* p2w = (const float*)d_in[14];
    const float* p2b = (const float*)d_in[15];
    const float* p3w = (const float*)d_in[16];
    const float* p3b = (const float*)d_in[17];
    const float* s1w = (const float*)d_in[18];
    const float* s1b = (const float*)d_in[19];
    const float* s2w = (const float*)d_in[20];
    const float* s2b = (const float*)d_in[21];
    const float* p4w = (const float*)d_in[22];
    const float* p4b = (const float*)d_in[23];

    float* out   = (float*)d_out;
    float* Zs    = out;                          // [6][B][64][512] col-major fp32
    float* bufA  = out + 6 * BND;
    float* bufB  = out + 7 * BND;                // ends exactly at AE size
    float* ws    = (float*)d_ws;
    float* bufC  = ws;                           // 2.1M floats
    float* hbuf  = ws + BND;                     // 2.1M floats (h, then X0)
    float* zfeat = ws + 2 * BND;                 // 16384
    unsigned short* w1h = (unsigned short*)(zfeat + 16384);  // 196608 shorts
    unsigned short* w1l = w1h + 6 * NN * DD;
    unsigned short* w2h = w1l + 6 * NN * DD;                 // 24576 shorts
    unsigned short* w2l = w2h + 6 * DD * DD;
    unsigned short* w3h = w2l + 6 * DD * DD;
    unsigned short* w3l = w3h + 6 * DD * DD;
    float* outc  = out + (long)BB * NN * NN;
    float* outsc = outc + BB * 4;

    const dim3 blk(256), gblk(512);
    const long ABATCH = (long)NN * NN;

    transW_split<<<dim3((6 * NN * DD + 255) / 256), blk, 0, stream>>>(W1, w1h, w1l, NN, 6 * NN * DD);
    transW_split<<<dim3((6 * DD * DD + 255) / 256), blk, 0, stream>>>(W2, w2h, w2l, DD, 6 * DD * DD);
    transW_split<<<dim3((6 * DD * DD + 255) / 256), blk, 0, stream>>>(W3, w3h, w3l, DD, 6 * DD * DD);

    const dim3 gridZ(8 * 64 * 2);   // z-triple fused: 1024 blocks
    const dim3 gridC(8 * 64);       // cheb: 512 blocks, nz=1

    auto cheb = [&](const float* bias, float* xout, bool rowOut) {
        gemm_mfma<false, true, false, false><<<gridC, gblk, 0, stream>>>(
            A, NN, ABATCH, Zs + 5 * BND, (long)ND, 0L, nullptr, Zs + 4 * BND, nullptr,
            2.f, 0.f, NN, bufA, 0L, 1);
        gemm_mfma<true, true, false, false><<<gridC, gblk, 0, stream>>>(
            A, NN, ABATCH, bufA, (long)ND, 0L, Zs + 5 * BND, Zs + 3 * BND, nullptr,
            2.f, -1.f, NN, bufB, 0L, 1);
        gemm_mfma<true, true, false, false><<<gridC, gblk, 0, stream>>>(
            A, NN, ABATCH, bufB, (long)ND, 0L, bufA, Zs + 2 * BND, nullptr,
            2.f, -1.f, NN, bufC, 0L, 1);
        gemm_mfma<true, true, false, false><<<gridC, gblk, 0, stream>>>(
            A, NN, ABATCH, bufC, (long)ND, 0L, bufB, Zs + 1 * BND, nullptr,
            2.f, -1.f, NN, bufA, 0L, 1);
        if (rowOut)
            gemm_mfma<true, true, true, true><<<gridC, gblk, 0, stream>>>(
                A, NN, ABATCH, bufA, (long)ND, 0L, bufC, Zs + 0 * BND, bias,
                1.f, -1.f, NN, xout, 0L, 1);
        else
            gemm_mfma<true, true, true, false><<<gridC, gblk, 0, stream>>>(
                A, NN, ABATCH, bufA, (long)ND, 0L, bufC, Zs + 0 * BND, bias,
                1.f, -1.f, NN, xout, 0L, 1);
    };

    // stage 1: Z_k = X @ W1[k]  (z-triple fused, W planes)
    gemm_z3<<<gridZ, gblk, 0, stream>>>(X, NN, ABATCH, w1h, w1l, NN, Zs, BND);
    cheb(b1v, bufB, false);
    ln_pool<<<dim3(64), blk, 0, stream>>>(bufB, g1, bt1, hbuf, zfeat, 0);

    // stage 2
    gemm_z3<<<gridZ, gblk, 0, stream>>>(hbuf, DD, (long)ND, w2h, w2l, DD, Zs, BND);
    cheb(b2v, bufB, false);
    ln_pool<<<dim3(64), blk, 0, stream>>>(bufB, g2, bt2, hbuf, zfeat, 128);

    // stage 3: X0 (row-major) -> hbuf (h already consumed)
    gemm_z3<<<gridZ, gblk, 0, stream>>>(hbuf, DD, (long)ND, w3h, w3l, DD, Zs, BND);
    cheb(b3v, hbuf, true);

    // AE = relu(X0 X0^T), zero diag
    outer_v19<<<dim3(8, 8, 64), blk, 0, stream>>>(hbuf, out);

    // heads
    heads<<<dim3(64), dim3(64), 0, stream>>>(
        zfeat, p1w, p1b, p2w, p2b, p3w, p3b, s1w, s1b, s2w, s2b, p4w, p4b, outc, outsc);
}